// Round 1
// baseline (289.272 us; speedup 1.0000x reference)
//
#include <hip/hip_runtime.h>
#include <hip/hip_bf16.h>
#include <math.h>

// Top2Router: x[4,4096,2048] fp32, W[8,2048] fp32, b[8] fp32
//   logits = x @ W^T + b ; gate = softmax(logits, -1) ; top2 of gate
// Outputs concatenated flat in d_out (fp32):
//   [0,      32768)  top2_val  [B,S,2]
//   [32768,  65536)  top2_idx  [B,S,2]  (indices stored as floats)
//   [65536, 196608)  gate      [B,S,8]
//
// Mapping: one lane per (token, expert). 8 tokens x 8 experts per wave64.
// Each lane accumulates the FULL D=2048 dot for its expert -> no reduction.
// Duplicate x addresses across the 8 expert-lanes of a token are merged by
// the coalescer / served by L1, so HBM traffic stays 1x (134 MB).

#define NTOK   16384   // B*S
#define DMODEL 2048
#define NEXP   8

__global__ __launch_bounds__(256) void top2router_kernel(
    const float* __restrict__ x,
    const float* __restrict__ W,
    const float* __restrict__ b,
    float* __restrict__ out)
{
    const int tid   = blockIdx.x * blockDim.x + threadIdx.x;
    const int e     = tid & 7;
    const int token = tid >> 3;

    const float* __restrict__ xrow = x + (size_t)token * DMODEL;
    const float* __restrict__ wrow = W + (size_t)e * DMODEL;

    // 4 independent accumulators (per float4 component) to break the
    // FMA dependency chain; also matches np's pairwise-ish error profile.
    float a0 = 0.f, a1 = 0.f, a2 = 0.f, a3 = 0.f;
#pragma unroll 8
    for (int d = 0; d < DMODEL; d += 4) {
        const float4 xv = *reinterpret_cast<const float4*>(xrow + d);
        const float4 wv = *reinterpret_cast<const float4*>(wrow + d);
        a0 = fmaf(xv.x, wv.x, a0);
        a1 = fmaf(xv.y, wv.y, a1);
        a2 = fmaf(xv.z, wv.z, a2);
        a3 = fmaf(xv.w, wv.w, a3);
    }
    const float logit = (a0 + a1) + (a2 + a3) + b[e];

    // ---- softmax across the 8 expert-lanes of this token ----
    float m = logit;
    #pragma unroll
    for (int s = 4; s; s >>= 1) m = fmaxf(m, __shfl_xor(m, s, 8));
    const float ex = expf(logit - m);
    float sum = ex;
    #pragma unroll
    for (int s = 4; s; s >>= 1) sum += __shfl_xor(sum, s, 8);
    const float gate = ex / sum;

    // gate output: 64 contiguous floats per wave -> coalesced
    out[65536 + token * NEXP + e] = gate;

    // ---- top-1 (ties -> lower index, matching jax.lax.top_k) ----
    float g1 = gate; int e1 = e;
    #pragma unroll
    for (int s = 4; s; s >>= 1) {
        const float og = __shfl_xor(g1, s, 8);
        const int   oe = __shfl_xor(e1, s, 8);
        if (og > g1 || (og == g1 && oe < e1)) { g1 = og; e1 = oe; }
    }
    // ---- top-2: mask the winner's lane, reduce again ----
    float g2 = (e == e1) ? -INFINITY : gate; int e2 = e;
    #pragma unroll
    for (int s = 4; s; s >>= 1) {
        const float og = __shfl_xor(g2, s, 8);
        const int   oe = __shfl_xor(e2, s, 8);
        if (og > g2 || (og == g2 && oe < e2)) { g2 = og; e2 = oe; }
    }

    if (e == 0) {
        out[token * 2 + 0]          = g1;
        out[token * 2 + 1]          = g2;
        out[32768 + token * 2 + 0]  = (float)e1;
        out[32768 + token * 2 + 1]  = (float)e2;
    }
}

extern "C" void kernel_launch(void* const* d_in, const int* in_sizes, int n_in,
                              void* d_out, int out_size, void* d_ws, size_t ws_size,
                              hipStream_t stream) {
    const float* x = (const float*)d_in[0];
    const float* W = (const float*)d_in[1];
    const float* b = (const float*)d_in[2];
    float* out = (float*)d_out;

    const int threads = NTOK * NEXP;          // 131072 lanes
    const int block = 256;
    const int grid = threads / block;         // 512 blocks
    top2router_kernel<<<grid, block, 0, stream>>>(x, W, b, out);
}

// Round 2
// 196.565 us; speedup vs baseline: 1.4716x; 1.4716x over previous
//
#include <hip/hip_runtime.h>
#include <hip/hip_bf16.h>
#include <math.h>

// Top2Router: x[4,4096,2048] fp32, W[8,2048] fp32, b[8] fp32
//   logits = x @ W^T + b ; gate = softmax(logits, -1) ; top2 of gate
// Outputs concatenated flat in d_out (fp32):
//   [0,      32768)  top2_val  [B,S,2]
//   [32768,  65536)  top2_idx  [B,S,2]  (indices stored as floats)
//   [65536, 196608)  gate      [B,S,8]
//
// R2 design: lane = st*8 + j. 8 tokens per wave (st = lane>>3), 8 d-slices
// per token (j = lane&7). Each x float4 load is 8 x 128B contiguous chunks
// = 1KB useful/instr (vs 128B in R1). W staged once in LDS (64KB/block);
// inner-loop W reads are ds_read_b128 with 8-way broadcast (conflict-free).
// Per-lane 8 expert partial dots -> 3-step reduce-scatter over j-lanes ->
// lane j holds logit[j] -> same 8-lane softmax/top2 epilogue as R1.

#define NTOK   16384   // B*S
#define DMODEL 2048
#define NEXP   8

__global__ __launch_bounds__(256, 2) void top2router_kernel(
    const float* __restrict__ x,
    const float* __restrict__ W,
    const float* __restrict__ b,
    float* __restrict__ out)
{
    __shared__ __align__(16) float sW[NEXP * DMODEL];   // 64 KB

    const int t = threadIdx.x;

    // ---- stage W into LDS: 4096 float4, 256 threads x 16 iters ----
    {
        const float4* __restrict__ Wv = reinterpret_cast<const float4*>(W);
        float4* sWv = reinterpret_cast<float4*>(sW);
#pragma unroll
        for (int i = 0; i < 16; ++i)
            sWv[i * 256 + t] = Wv[i * 256 + t];
    }
    __syncthreads();

    const int lane = t & 63;
    const int wave = t >> 6;
    const int j    = lane & 7;     // d-slice id (becomes expert id after reduce-scatter)
    const int st   = lane >> 3;    // sub-token 0..7
    const int token = (blockIdx.x * 4 + wave) * 8 + st;

    const float* __restrict__ xptr = x + (size_t)token * DMODEL + (j << 2);

    // ---- main loop: 64 iters, d = k*32 + j*4 ----
    float4 acc[NEXP];
#pragma unroll
    for (int e = 0; e < NEXP; ++e) acc[e] = make_float4(0.f, 0.f, 0.f, 0.f);

#pragma unroll 2
    for (int k = 0; k < 64; ++k) {
        const float4 xv = *reinterpret_cast<const float4*>(xptr + (k << 5));
#pragma unroll
        for (int e = 0; e < NEXP; ++e) {
            const float4 wv =
                *reinterpret_cast<const float4*>(&sW[e * DMODEL + (k << 5) + (j << 2)]);
            acc[e].x = fmaf(xv.x, wv.x, acc[e].x);
            acc[e].y = fmaf(xv.y, wv.y, acc[e].y);
            acc[e].z = fmaf(xv.z, wv.z, acc[e].z);
            acc[e].w = fmaf(xv.w, wv.w, acc[e].w);
        }
    }

    // ---- fold float4 -> scalar per expert ----
    float v0 = (acc[0].x + acc[0].y) + (acc[0].z + acc[0].w);
    float v1 = (acc[1].x + acc[1].y) + (acc[1].z + acc[1].w);
    float v2 = (acc[2].x + acc[2].y) + (acc[2].z + acc[2].w);
    float v3 = (acc[3].x + acc[3].y) + (acc[3].z + acc[3].w);
    float v4 = (acc[4].x + acc[4].y) + (acc[4].z + acc[4].w);
    float v5 = (acc[5].x + acc[5].y) + (acc[5].z + acc[5].w);
    float v6 = (acc[6].x + acc[6].y) + (acc[6].z + acc[6].w);
    float v7 = (acc[7].x + acc[7].y) + (acc[7].z + acc[7].w);

    // ---- reduce-scatter over the 8 j-lanes: lane j ends with logit[j] ----
    // step 1 (xor 1): keep experts with e&1 == j&1
    float s0 = v0 + __shfl_xor(v0, 1, 8);
    float s1 = v1 + __shfl_xor(v1, 1, 8);
    float s2 = v2 + __shfl_xor(v2, 1, 8);
    float s3 = v3 + __shfl_xor(v3, 1, 8);
    float s4 = v4 + __shfl_xor(v4, 1, 8);
    float s5 = v5 + __shfl_xor(v5, 1, 8);
    float s6 = v6 + __shfl_xor(v6, 1, 8);
    float s7 = v7 + __shfl_xor(v7, 1, 8);
    const bool b0 = (j & 1);
    float t0 = b0 ? s1 : s0;   // t_i -> e = 2i + (j&1)
    float t1 = b0 ? s3 : s2;
    float t2 = b0 ? s5 : s4;
    float t3 = b0 ? s7 : s6;
    // step 2 (xor 2): keep i with i&1 == (j>>1)&1
    float p0 = t0 + __shfl_xor(t0, 2, 8);
    float p1 = t1 + __shfl_xor(t1, 2, 8);
    float p2 = t2 + __shfl_xor(t2, 2, 8);
    float p3 = t3 + __shfl_xor(t3, 2, 8);
    const bool b1 = (j & 2);
    float u0 = b1 ? p1 : p0;   // u_k -> e = 4k + 2*((j>>1)&1) + (j&1)
    float u1 = b1 ? p3 : p2;
    // step 3 (xor 4): keep k == (j>>2)&1
    float q0 = u0 + __shfl_xor(u0, 4, 8);
    float q1 = u1 + __shfl_xor(u1, 4, 8);
    const float dot = (j & 4) ? q1 : q0;   // == full dot for expert e = j

    const float logit = dot + b[j];

    // ---- softmax across the 8 expert-lanes of this token ----
    float m = logit;
#pragma unroll
    for (int s = 4; s; s >>= 1) m = fmaxf(m, __shfl_xor(m, s, 8));
    const float ex = expf(logit - m);
    float sum = ex;
#pragma unroll
    for (int s = 4; s; s >>= 1) sum += __shfl_xor(sum, s, 8);
    const float gate = ex / sum;

    // gate out: 64 contiguous floats per wave -> coalesced
    out[65536 + token * NEXP + j] = gate;

    // ---- top-1 (ties -> lower index) ----
    float g1 = gate; int e1 = j;
#pragma unroll
    for (int s = 4; s; s >>= 1) {
        const float og = __shfl_xor(g1, s, 8);
        const int   oe = __shfl_xor(e1, s, 8);
        if (og > g1 || (og == g1 && oe < e1)) { g1 = og; e1 = oe; }
    }
    // ---- top-2: mask winner, reduce again ----
    float g2 = (j == e1) ? -INFINITY : gate; int e2 = j;
#pragma unroll
    for (int s = 4; s; s >>= 1) {
        const float og = __shfl_xor(g2, s, 8);
        const int   oe = __shfl_xor(e2, s, 8);
        if (og > g2 || (og == g2 && oe < e2)) { g2 = og; e2 = oe; }
    }

    if (j == 0) {
        out[token * 2 + 0]         = g1;
        out[token * 2 + 1]         = g2;
        out[32768 + token * 2 + 0] = (float)e1;
        out[32768 + token * 2 + 1] = (float)e2;
    }
}

extern "C" void kernel_launch(void* const* d_in, const int* in_sizes, int n_in,
                              void* d_out, int out_size, void* d_ws, size_t ws_size,
                              hipStream_t stream) {
    const float* x = (const float*)d_in[0];
    const float* W = (const float*)d_in[1];
    const float* b = (const float*)d_in[2];
    float* out = (float*)d_out;

    // 8 tokens/wave, 4 waves/block -> 32 tokens/block; 16384/32 = 512 blocks
    top2router_kernel<<<512, 256, 0, stream>>>(x, W, b, out);
}

// Round 3
// 195.050 us; speedup vs baseline: 1.4831x; 1.0078x over previous
//
#include <hip/hip_runtime.h>
#include <hip/hip_bf16.h>
#include <math.h>

// Top2Router: x[4,4096,2048] fp32, W[8,2048] fp32, b[8] fp32
//   logits = x @ W^T + b ; gate = softmax(logits, -1) ; top2 of gate
// d_out (fp32, concat): [0,32768) top2_val | [32768,65536) top2_idx |
//                       [65536,196608) gate
//
// R3: A=16 amortization. Lane = st*8+j (8 sub-tokens x 8 d-slices); each lane
// handles T=2 tokens (st and st+8), so one ds_read_b128 of W feeds 16 tokens'
// FMAs -> LDS pipe ~10us/CU, under the 21us HBM floor. 256 blocks (1/CU),
// 4 waves/CU; latency hidden by explicit x-prefetch of iteration k+1 (>=4
// independent 1KB wave-loads in flight per wave).

#define NTOK   16384
#define DM     2048
#define NE     8

__device__ __forceinline__ float fold4(const float4 a) {
    return (a.x + a.y) + (a.z + a.w);
}

// Reduce-scatter 8 per-lane expert partials across the 8 j-lanes of a token:
// returns the full dot for expert e == j. (Verified in R2.)
__device__ __forceinline__ float reduce_scatter8(const float4* acc, const int j) {
    float v0 = fold4(acc[0]), v1 = fold4(acc[1]), v2 = fold4(acc[2]), v3 = fold4(acc[3]);
    float v4 = fold4(acc[4]), v5 = fold4(acc[5]), v6 = fold4(acc[6]), v7 = fold4(acc[7]);
    float s0 = v0 + __shfl_xor(v0, 1, 8);
    float s1 = v1 + __shfl_xor(v1, 1, 8);
    float s2 = v2 + __shfl_xor(v2, 1, 8);
    float s3 = v3 + __shfl_xor(v3, 1, 8);
    float s4 = v4 + __shfl_xor(v4, 1, 8);
    float s5 = v5 + __shfl_xor(v5, 1, 8);
    float s6 = v6 + __shfl_xor(v6, 1, 8);
    float s7 = v7 + __shfl_xor(v7, 1, 8);
    const bool b0 = (j & 1);
    float t0 = b0 ? s1 : s0;
    float t1 = b0 ? s3 : s2;
    float t2 = b0 ? s5 : s4;
    float t3 = b0 ? s7 : s6;
    float p0 = t0 + __shfl_xor(t0, 2, 8);
    float p1 = t1 + __shfl_xor(t1, 2, 8);
    float p2 = t2 + __shfl_xor(t2, 2, 8);
    float p3 = t3 + __shfl_xor(t3, 2, 8);
    const bool b1 = (j & 2);
    float u0 = b1 ? p1 : p0;
    float u1 = b1 ? p3 : p2;
    float q0 = u0 + __shfl_xor(u0, 4, 8);
    float q1 = u1 + __shfl_xor(u1, 4, 8);
    return (j & 4) ? q1 : q0;
}

// 8-lane softmax + top2 epilogue for one token. (Verified in R1/R2.)
__device__ __forceinline__ void softmax_top2(const float logit, const int j,
                                             const int token, float* __restrict__ out) {
    float m = logit;
#pragma unroll
    for (int s = 4; s; s >>= 1) m = fmaxf(m, __shfl_xor(m, s, 8));
    const float ex = expf(logit - m);
    float sum = ex;
#pragma unroll
    for (int s = 4; s; s >>= 1) sum += __shfl_xor(sum, s, 8);
    const float gate = ex / sum;

    out[65536 + token * NE + j] = gate;

    float g1 = gate; int e1 = j;
#pragma unroll
    for (int s = 4; s; s >>= 1) {
        const float og = __shfl_xor(g1, s, 8);
        const int   oe = __shfl_xor(e1, s, 8);
        if (og > g1 || (og == g1 && oe < e1)) { g1 = og; e1 = oe; }
    }
    float g2 = (j == e1) ? -INFINITY : gate; int e2 = j;
#pragma unroll
    for (int s = 4; s; s >>= 1) {
        const float og = __shfl_xor(g2, s, 8);
        const int   oe = __shfl_xor(e2, s, 8);
        if (og > g2 || (og == g2 && oe < e2)) { g2 = og; e2 = oe; }
    }
    if (j == 0) {
        out[token * 2 + 0]         = g1;
        out[token * 2 + 1]         = g2;
        out[32768 + token * 2 + 0] = (float)e1;
        out[32768 + token * 2 + 1] = (float)e2;
    }
}

__global__ __launch_bounds__(256, 1) void top2router_kernel(
    const float* __restrict__ x,
    const float* __restrict__ W,
    const float* __restrict__ b,
    float* __restrict__ out)
{
    __shared__ __align__(16) float sW[NE * DM];   // 64 KB

    const int t = threadIdx.x;

    // stage W into LDS: 4096 float4 over 256 threads
    {
        const float4* __restrict__ Wv = reinterpret_cast<const float4*>(W);
        float4* sWv = reinterpret_cast<float4*>(sW);
#pragma unroll
        for (int i = 0; i < 16; ++i)
            sWv[i * 256 + t] = Wv[i * 256 + t];
    }
    __syncthreads();

    const int lane = t & 63;
    const int wave = t >> 6;
    const int j    = lane & 7;    // d-slice id == expert id after reduce-scatter
    const int st   = lane >> 3;   // sub-token 0..7
    const int base = (blockIdx.x * 4 + wave) * 16;  // 16 tokens per wave
    const int tok0 = base + st;
    const int tok1 = base + st + 8;

    const float* __restrict__ xp0 = x + (size_t)tok0 * DM + (j << 2);
    const float* __restrict__ xp1 = x + (size_t)tok1 * DM + (j << 2);
    const float bj = b[j];

    float4 acc0[NE], acc1[NE];
#pragma unroll
    for (int e = 0; e < NE; ++e) {
        acc0[e] = make_float4(0.f, 0.f, 0.f, 0.f);
        acc1[e] = make_float4(0.f, 0.f, 0.f, 0.f);
    }

    // software pipeline: x loads for k+1 issued before FMAs of k
    float4 xa0 = *reinterpret_cast<const float4*>(xp0);
    float4 xa1 = *reinterpret_cast<const float4*>(xp1);

#pragma unroll 3
    for (int k = 0; k < 63; ++k) {
        const float4 xb0 = *reinterpret_cast<const float4*>(xp0 + ((k + 1) << 5));
        const float4 xb1 = *reinterpret_cast<const float4*>(xp1 + ((k + 1) << 5));
        const float* wbase = &sW[(k << 5) + (j << 2)];
#pragma unroll
        for (int e = 0; e < NE; ++e) {
            const float4 wv = *reinterpret_cast<const float4*>(wbase + e * DM);
            acc0[e].x = fmaf(xa0.x, wv.x, acc0[e].x);
            acc0[e].y = fmaf(xa0.y, wv.y, acc0[e].y);
            acc0[e].z = fmaf(xa0.z, wv.z, acc0[e].z);
            acc0[e].w = fmaf(xa0.w, wv.w, acc0[e].w);
            acc1[e].x = fmaf(xa1.x, wv.x, acc1[e].x);
            acc1[e].y = fmaf(xa1.y, wv.y, acc1[e].y);
            acc1[e].z = fmaf(xa1.z, wv.z, acc1[e].z);
            acc1[e].w = fmaf(xa1.w, wv.w, acc1[e].w);
        }
        xa0 = xb0;
        xa1 = xb1;
    }
    {   // peeled last iteration k = 63
        const float* wbase = &sW[(63 << 5) + (j << 2)];
#pragma unroll
        for (int e = 0; e < NE; ++e) {
            const float4 wv = *reinterpret_cast<const float4*>(wbase + e * DM);
            acc0[e].x = fmaf(xa0.x, wv.x, acc0[e].x);
            acc0[e].y = fmaf(xa0.y, wv.y, acc0[e].y);
            acc0[e].z = fmaf(xa0.z, wv.z, acc0[e].z);
            acc0[e].w = fmaf(xa0.w, wv.w, acc0[e].w);
            acc1[e].x = fmaf(xa1.x, wv.x, acc1[e].x);
            acc1[e].y = fmaf(xa1.y, wv.y, acc1[e].y);
            acc1[e].z = fmaf(xa1.z, wv.z, acc1[e].z);
            acc1[e].w = fmaf(xa1.w, wv.w, acc1[e].w);
        }
    }

    const float logit0 = reduce_scatter8(acc0, j) + bj;
    const float logit1 = reduce_scatter8(acc1, j) + bj;

    softmax_top2(logit0, j, tok0, out);
    softmax_top2(logit1, j, tok1, out);
}

extern "C" void kernel_launch(void* const* d_in, const int* in_sizes, int n_in,
                              void* d_out, int out_size, void* d_ws, size_t ws_size,
                              hipStream_t stream) {
    const float* x = (const float*)d_in[0];
    const float* W = (const float*)d_in[1];
    const float* b = (const float*)d_in[2];
    float* out = (float*)d_out;

    // 16 tokens/wave (8 st x T=2), 4 waves/block -> 64 tokens/block;
    // 16384/64 = 256 blocks = 1 block/CU.
    top2router_kernel<<<256, 256, 0, stream>>>(x, W, b, out);
}

// Round 4
// 194.823 us; speedup vs baseline: 1.4848x; 1.0012x over previous
//
#include <hip/hip_runtime.h>
#include <hip/hip_bf16.h>
#include <math.h>

// Top2Router: x[4,4096,2048] fp32, W[8,2048] fp32, b[8] fp32
//   logits = x @ W^T + b ; gate = softmax(logits, -1) ; top2 of gate
// d_out (fp32, concat): [0,32768) top2_val | [32768,65536) top2_idx |
//                       [65536,196608) gate
//
// R4: same A=16 decomposition as R3 (lane = st*8+j, T=2 tokens/lane, W in
// 64KB LDS, 8-way broadcast ds_read_b128), but prefetch depth 4 on x:
// a ring of 4 k-iterations (8 float4 = 8KB in flight per wave, 32KB/CU)
// so global latency (~900-2200 cyc) is covered by 4 groups of work-ahead.
// R3 post-mortem showed the kernel was latency-bound (2200 cyc/iter) with
// depth-1 prefetch; VALU 3.4us and LDS 10us are far under the 21us HBM floor.

#define NTOK   16384
#define DM     2048
#define NE     8

__device__ __forceinline__ float fold4(const float4 a) {
    return (a.x + a.y) + (a.z + a.w);
}

// Reduce-scatter 8 per-lane expert partials across the 8 j-lanes of a token:
// returns the full dot for expert e == j. (Verified R2/R3.)
__device__ __forceinline__ float reduce_scatter8(const float4* acc, const int j) {
    float v0 = fold4(acc[0]), v1 = fold4(acc[1]), v2 = fold4(acc[2]), v3 = fold4(acc[3]);
    float v4 = fold4(acc[4]), v5 = fold4(acc[5]), v6 = fold4(acc[6]), v7 = fold4(acc[7]);
    float s0 = v0 + __shfl_xor(v0, 1, 8);
    float s1 = v1 + __shfl_xor(v1, 1, 8);
    float s2 = v2 + __shfl_xor(v2, 1, 8);
    float s3 = v3 + __shfl_xor(v3, 1, 8);
    float s4 = v4 + __shfl_xor(v4, 1, 8);
    float s5 = v5 + __shfl_xor(v5, 1, 8);
    float s6 = v6 + __shfl_xor(v6, 1, 8);
    float s7 = v7 + __shfl_xor(v7, 1, 8);
    const bool b0 = (j & 1);
    float t0 = b0 ? s1 : s0;
    float t1 = b0 ? s3 : s2;
    float t2 = b0 ? s5 : s4;
    float t3 = b0 ? s7 : s6;
    float p0 = t0 + __shfl_xor(t0, 2, 8);
    float p1 = t1 + __shfl_xor(t1, 2, 8);
    float p2 = t2 + __shfl_xor(t2, 2, 8);
    float p3 = t3 + __shfl_xor(t3, 2, 8);
    const bool b1 = (j & 2);
    float u0 = b1 ? p1 : p0;
    float u1 = b1 ? p3 : p2;
    float q0 = u0 + __shfl_xor(u0, 4, 8);
    float q1 = u1 + __shfl_xor(u1, 4, 8);
    return (j & 4) ? q1 : q0;
}

// 8-lane softmax + top2 epilogue for one token. (Verified R1-R3.)
__device__ __forceinline__ void softmax_top2(const float logit, const int j,
                                             const int token, float* __restrict__ out) {
    float m = logit;
#pragma unroll
    for (int s = 4; s; s >>= 1) m = fmaxf(m, __shfl_xor(m, s, 8));
    const float ex = expf(logit - m);
    float sum = ex;
#pragma unroll
    for (int s = 4; s; s >>= 1) sum += __shfl_xor(sum, s, 8);
    const float gate = ex / sum;

    out[65536 + token * NE + j] = gate;

    float g1 = gate; int e1 = j;
#pragma unroll
    for (int s = 4; s; s >>= 1) {
        const float og = __shfl_xor(g1, s, 8);
        const int   oe = __shfl_xor(e1, s, 8);
        if (og > g1 || (og == g1 && oe < e1)) { g1 = og; e1 = oe; }
    }
    float g2 = (j == e1) ? -INFINITY : gate; int e2 = j;
#pragma unroll
    for (int s = 4; s; s >>= 1) {
        const float og = __shfl_xor(g2, s, 8);
        const int   oe = __shfl_xor(e2, s, 8);
        if (og > g2 || (og == g2 && oe < e2)) { g2 = og; e2 = oe; }
    }
    if (j == 0) {
        out[token * 2 + 0]         = g1;
        out[token * 2 + 1]         = g2;
        out[32768 + token * 2 + 0] = (float)e1;
        out[32768 + token * 2 + 1] = (float)e2;
    }
}

__device__ __forceinline__ void fma_group(const float* __restrict__ wbase,
                                          const float4 xa0, const float4 xa1,
                                          float4* __restrict__ acc0,
                                          float4* __restrict__ acc1) {
#pragma unroll
    for (int e = 0; e < NE; ++e) {
        const float4 wv = *reinterpret_cast<const float4*>(wbase + e * DM);
        acc0[e].x = fmaf(xa0.x, wv.x, acc0[e].x);
        acc0[e].y = fmaf(xa0.y, wv.y, acc0[e].y);
        acc0[e].z = fmaf(xa0.z, wv.z, acc0[e].z);
        acc0[e].w = fmaf(xa0.w, wv.w, acc0[e].w);
        acc1[e].x = fmaf(xa1.x, wv.x, acc1[e].x);
        acc1[e].y = fmaf(xa1.y, wv.y, acc1[e].y);
        acc1[e].z = fmaf(xa1.z, wv.z, acc1[e].z);
        acc1[e].w = fmaf(xa1.w, wv.w, acc1[e].w);
    }
}

__global__ __launch_bounds__(256, 1) void top2router_kernel(
    const float* __restrict__ x,
    const float* __restrict__ W,
    const float* __restrict__ b,
    float* __restrict__ out)
{
    __shared__ __align__(16) float sW[NE * DM];   // 64 KB

    const int t = threadIdx.x;

    // stage W into LDS: 4096 float4 over 256 threads
    {
        const float4* __restrict__ Wv = reinterpret_cast<const float4*>(W);
        float4* sWv = reinterpret_cast<float4*>(sW);
#pragma unroll
        for (int i = 0; i < 16; ++i)
            sWv[i * 256 + t] = Wv[i * 256 + t];
    }
    __syncthreads();

    const int lane = t & 63;
    const int wave = t >> 6;
    const int j    = lane & 7;    // d-slice id == expert id after reduce-scatter
    const int st   = lane >> 3;   // sub-token 0..7
    const int base = (blockIdx.x * 4 + wave) * 16;  // 16 tokens per wave
    const int tok0 = base + st;
    const int tok1 = base + st + 8;

    const float* __restrict__ xp0 = x + (size_t)tok0 * DM + (j << 2);
    const float* __restrict__ xp1 = x + (size_t)tok1 * DM + (j << 2);
    const float bj = b[j];

    float4 acc0[NE], acc1[NE];
#pragma unroll
    for (int e = 0; e < NE; ++e) {
        acc0[e] = make_float4(0.f, 0.f, 0.f, 0.f);
        acc1[e] = make_float4(0.f, 0.f, 0.f, 0.f);
    }

    // ---- prefetch ring, depth 4: pb holds x for iterations kk..kk+3 ----
    float4 pb0[4], pb1[4];
#pragma unroll
    for (int p = 0; p < 4; ++p) {
        pb0[p] = *reinterpret_cast<const float4*>(xp0 + (p << 5));
        pb1[p] = *reinterpret_cast<const float4*>(xp1 + (p << 5));
    }

    // groups kk = 0..56: compute kk..kk+3 while loading kk+4..kk+7
#pragma unroll 3
    for (int kk = 0; kk < 60; kk += 4) {
        float4 cb0[4], cb1[4];
#pragma unroll
        for (int p = 0; p < 4; ++p) { cb0[p] = pb0[p]; cb1[p] = pb1[p]; }
#pragma unroll
        for (int p = 0; p < 4; ++p) {
            pb0[p] = *reinterpret_cast<const float4*>(xp0 + ((kk + 4 + p) << 5));
            pb1[p] = *reinterpret_cast<const float4*>(xp1 + ((kk + 4 + p) << 5));
        }
#pragma unroll
        for (int p = 0; p < 4; ++p)
            fma_group(&sW[((kk + p) << 5) + (j << 2)], cb0[p], cb1[p], acc0, acc1);
    }
    // last group kk = 60..63: compute from pb, no prefetch
#pragma unroll
    for (int p = 0; p < 4; ++p)
        fma_group(&sW[((60 + p) << 5) + (j << 2)], pb0[p], pb1[p], acc0, acc1);

    const float logit0 = reduce_scatter8(acc0, j) + bj;
    const float logit1 = reduce_scatter8(acc1, j) + bj;

    softmax_top2(logit0, j, tok0, out);
    softmax_top2(logit1, j, tok1, out);
}

extern "C" void kernel_launch(void* const* d_in, const int* in_sizes, int n_in,
                              void* d_out, int out_size, void* d_ws, size_t ws_size,
                              hipStream_t stream) {
    const float* x = (const float*)d_in[0];
    const float* W = (const float*)d_in[1];
    const float* b = (const float*)d_in[2];
    float* out = (float*)d_out;

    // 16 tokens/wave (8 st x T=2), 4 waves/block -> 64 tokens/block;
    // 16384/64 = 256 blocks = 1 block/CU.
    top2router_kernel<<<256, 256, 0, stream>>>(x, W, b, out);
}